// Round 9
// baseline (197.447 us; speedup 1.0000x reference)
//
#include <hip/hip_runtime.h>

#define COLS 2048
#define KSEL 256
#define TPB  256
#define RPB  4            // rows per block = waves per block (no barriers)
#define RSTRIDE 1296      // LDS words per row region
// Per-row region (word offsets):
//   P1: 1024-bin hist, bin b at addr b + 4*(b>>4)  -> [0..1275]
//   after P1 dead; reused: [0..255] fallback 256-bin hist,
//                          [256..511] compact list BUF (cap 256),
//                          [512..575] final list R2 (cap 64)
#define BUFOFF 256
#define R2OFF  512

__device__ __forceinline__ unsigned rfl(unsigned v) {
    return (unsigned)__builtin_amdgcn_readfirstlane((int)v);
}
// score = |x*imp| bits; identical to |x|*|imp| (sign only affects sign bit)
__device__ __forceinline__ unsigned scoreOf(float xv, float iv) {
    return __float_as_uint(xv * iv) & 0x7FFFFFFFu;
}

// One WAVE per row, zero __syncthreads (wave-private LDS regions).
// Coalesced chunk layout: lane l owns cols 4l + 256c + j (c=0..7, j=0..3).
// ONLY sc[32] lives in VGPRs (~60 total, no spill); x is re-read in the
// epilogue -- the re-read is L2-hit (in-flight rows' footprint ~2MB/XCD).
// P1: 1024-bin radix pass on bits[30:21]; then wave ballot-radix on the
// <=64 survivors (common), with exact list/full fallback passes.
// Tie handling matches jax.lax.top_k (lower column index first).
__global__ __launch_bounds__(TPB)
void CompetitiveSelection_topk_kernel(const float* __restrict__ x,
                                      const float* __restrict__ imp,
                                      float* __restrict__ out)
{
    __shared__ __align__(16) unsigned int lds[RPB * RSTRIDE];
    const int lane = threadIdx.x & 63;
    const int wid  = threadIdx.x >> 6;
    unsigned int* reg = lds + wid * RSTRIDE;
    const int row = blockIdx.x * RPB + wid;
    const long gb = (long)row * COLS + 4 * lane;
    const float* xr = x + gb;
    const float* ir = imp + 4 * lane;

    unsigned T = 0, kk = KSEL, na = 0;
    unsigned hm = 0xFFE00000u;             // determined-bit mask after P1
    int nb = 21;                           // undetermined low bits

    // broadcast helper for scan results
    auto bcast = [&](int cc, unsigned cab, unsigned cnb, unsigned curT,
                     int shift, unsigned curkk) {
        unsigned long long m = __ballot(cc >= 0);   // exactly one lane
        int src = __ffsll(m) - 1;
        T  = rfl(curT | ((unsigned)__shfl(cc, src) << shift));
        kk = rfl(curkk - (unsigned)__shfl((int)cab, src));
        na = rfl((unsigned)__shfl((int)cnb, src));
    };

    // ---- clear P1 hist (1280 padded words, 5 x uint4 per lane) ----
    {
        const uint4 z4 = make_uint4(0, 0, 0, 0);
#pragma unroll
        for (int k = 0; k < 5; ++k) *(uint4*)&reg[20 * lane + 4 * k] = z4;
    }

    // ---- fused load + score-once + P1 atomics (bits[30:21], 1024 bins) ----
    unsigned sc[32];
    {
#pragma unroll
        for (int c = 0; c < 8; ++c) {
            float4 xa = *(const float4*)(xr + 256 * c);
            float4 ia = *(const float4*)(ir + 256 * c);
            sc[4*c+0] = scoreOf(xa.x, ia.x);
            sc[4*c+1] = scoreOf(xa.y, ia.y);
            sc[4*c+2] = scoreOf(xa.z, ia.z);
            sc[4*c+3] = scoreOf(xa.w, ia.w);
#pragma unroll
            for (int j = 0; j < 4; ++j) {
                unsigned d = sc[4*c+j] >> 21;
                atomicAdd(&reg[d + 4 * (d >> 4)], 1u);
            }
        }
        // lane owns bins [16*lane .. 16*lane+15] at words 20*lane + m
        uint4 h0 = *(const uint4*)&reg[20 * lane + 0];
        uint4 h1 = *(const uint4*)&reg[20 * lane + 4];
        uint4 h2 = *(const uint4*)&reg[20 * lane + 8];
        uint4 h3 = *(const uint4*)&reg[20 * lane + 12];
        unsigned cnt[16] = {h0.x, h0.y, h0.z, h0.w, h1.x, h1.y, h1.z, h1.w,
                            h2.x, h2.y, h2.z, h2.w, h3.x, h3.y, h3.z, h3.w};
        unsigned tot = 0;
#pragma unroll
        for (int m = 0; m < 16; ++m) tot += cnt[m];
        unsigned S = tot;                  // suffix sum over lanes >= lane
#pragma unroll
        for (int off = 1; off < 64; off <<= 1) {
            unsigned u = __shfl_down(S, off);
            if (lane + off < 64) S += u;
        }
        unsigned above = S - tot;          // count in bins > 16*lane+15
        int cc = -1; unsigned cab = 0, cnb = 0;
#pragma unroll
        for (int b = 15; b >= 0; --b) {
            if (cc < 0 && above < KSEL && above + cnt[b] >= KSEL) {
                cc = 16 * lane + b; cab = above; cnb = cnt[b];
            }
            above += cnt[b];
        }
        bcast(cc, cab, cnb, 0u, 21, KSEL);
    }

    unsigned nlist = 0; bool haveList = false;

    // cheap compaction: per-lane count -> one prefix scan -> exec-masked
    // sequential writes (static sc indices; lanes write disjoint LDS ranges)
    auto compactTo = [&](unsigned dstOff) -> unsigned {
        unsigned cnt = 0;
#pragma unroll
        for (int j = 0; j < 32; ++j) cnt += ((sc[j] & hm) == T) ? 1u : 0u;
        unsigned S = cnt;
#pragma unroll
        for (int off = 1; off < 64; off <<= 1) {
            unsigned u = __shfl_up(S, off);
            if (lane >= off) S += u;
        }
        unsigned p = dstOff + S - cnt;     // exclusive prefix = my write base
#pragma unroll
        for (int j = 0; j < 32; ++j)
            if ((sc[j] & hm) == T) reg[p++] = sc[j];
        return rfl((unsigned)__shfl((int)S, 63));
    };

    // 256-bin scanfind over reg[0..255] (4 bins/lane)
    auto scanfind256 = [&](int s) {
        uint4 h = *(const uint4*)&reg[4 * lane];
        unsigned cnt[4] = {h.x, h.y, h.z, h.w};
        unsigned tot = cnt[0] + cnt[1] + cnt[2] + cnt[3];
        unsigned S = tot;
#pragma unroll
        for (int off = 1; off < 64; off <<= 1) {
            unsigned u = __shfl_down(S, off);
            if (lane + off < 64) S += u;
        }
        unsigned above = S - tot;
        int cc = -1; unsigned cab = 0, cnb = 0;
#pragma unroll
        for (int b = 3; b >= 0; --b) {
            if (cc < 0 && above < kk && above + cnt[b] >= kk) {
                cc = 4 * lane + b; cab = above; cnb = cnt[b];
            }
            above += cnt[b];
        }
        bcast(cc, cab, cnb, T, s, kk);
    };

    // fallback refinement passes while the boundary bin stays fat
    while (na > 64u && nb > 0) {
        int s = (nb > 8) ? (nb - 8) : 0;
        if (!haveList && na <= 256u) { nlist = compactTo(BUFOFF); haveList = true; }
        *(uint4*)&reg[4 * lane] = make_uint4(0, 0, 0, 0);   // clear 256-bin hist
        if (haveList) {
            for (unsigned idx = (unsigned)lane; idx < nlist; idx += 64u) {
                unsigned v = reg[BUFOFF + idx];
                if ((v & hm) == T) atomicAdd(&reg[(v >> s) & 255u], 1u);
            }
        } else {
#pragma unroll
            for (int j = 0; j < 32; ++j)
                if ((sc[j] & hm) == T) atomicAdd(&reg[(sc[j] >> s) & 255u], 1u);
        }
        scanfind256(s);
        nb = s; hm |= (0xFFu << s);
    }

    unsigned ne;
    if (na > 64u) {
        ne = na;                           // nb==0: T exact, na == #equals
    } else if (nb > 0) {
        // gather <=64 survivors into R2
        if (haveList) {
            unsigned run2 = 0;
            const unsigned nit = (nlist + 63u) >> 6;
            for (unsigned k = 0; k < nit; ++k) {
                unsigned idx = (unsigned)lane + 64u * k;
                bool inb = idx < nlist;
                unsigned v = inb ? reg[BUFOFF + idx] : 0u;
                bool act = inb && ((v & hm) == T);
                unsigned long long m = __ballot(act);
                unsigned c0 = __builtin_amdgcn_mbcnt_lo((unsigned)m, 0u);
                unsigned pos = __builtin_amdgcn_mbcnt_hi((unsigned)(m >> 32), c0);
                if (act) reg[R2OFF + run2 + pos] = v;
                run2 += (unsigned)__popcll(m);
            }
        } else {
            compactTo(R2OFF);
        }
        // wave ballot-radix over remaining nb bits (exact)
        unsigned v = reg[R2OFF + lane];
        unsigned long long M = __ballot((unsigned)lane < na);
        unsigned tl = 0, k2 = kk;
        for (int b = nb - 1; b >= 0; --b) {
            unsigned long long ones = __ballot((v >> b) & 1u) & M;
            unsigned c1 = (unsigned)__popcll(ones);
            if (c1 >= k2) { M = ones; tl |= (1u << b); }
            else          { M &= ~ones; k2 -= c1; }
        }
        T = rfl(T | tl); kk = rfl(k2); ne = rfl((unsigned)__popcll(M));
    } else {
        ne = na;
    }

    // ---- epilogue: re-read x (L2-hit), apply exact mask (coalesced) ----
    float* orow = out + gb;
    if (ne == kk) {                        // no boundary-tie split (common)
#pragma unroll
        for (int c = 0; c < 8; ++c) {
            float4 xa = *(const float4*)(xr + 256 * c);
            float4 o;
            o.x = (sc[4*c+0] >= T) ? xa.x : 0.0f;
            o.y = (sc[4*c+1] >= T) ? xa.y : 0.0f;
            o.z = (sc[4*c+2] >= T) ? xa.z : 0.0f;
            o.w = (sc[4*c+3] >= T) ? xa.w : 0.0f;
            *(float4*)(orow + 256 * c) = o;
        }
    } else {
        // split ties by lowest column: col = 256c + 4*lane + j, ordered (c,lane,j)
        unsigned tot = 0;
#pragma unroll
        for (int c = 0; c < 8; ++c) {
            float4 xa = *(const float4*)(xr + 256 * c);
            unsigned eqc = (sc[4*c+0] == T) + (sc[4*c+1] == T) +
                           (sc[4*c+2] == T) + (sc[4*c+3] == T);
            unsigned S = eqc;
#pragma unroll
            for (int off = 1; off < 64; off <<= 1) {
                unsigned u = __shfl_up(S, off);
                if (lane >= off) S += u;
            }
            unsigned ebase = tot + S - eqc;  // equals in lower columns
            float xv[4] = {xa.x, xa.y, xa.z, xa.w};
            float o[4];
#pragma unroll
            for (int j = 0; j < 4; ++j) {
                bool pick = sc[4*c+j] > T;
                if (sc[4*c+j] == T) { pick = (ebase < kk); ebase += 1; }
                o[j] = pick ? xv[j] : 0.0f;
            }
            *(float4*)(orow + 256 * c) = make_float4(o[0], o[1], o[2], o[3]);
            tot += rfl((unsigned)__shfl((int)S, 63));
        }
    }
}

extern "C" void kernel_launch(void* const* d_in, const int* in_sizes, int n_in,
                              void* d_out, int out_size, void* d_ws, size_t ws_size,
                              hipStream_t stream)
{
    const float* x   = (const float*)d_in[0];
    const float* imp = (const float*)d_in[1];
    float* out       = (float*)d_out;

    const int rows = in_sizes[0] / COLS;     // 32768
    CompetitiveSelection_topk_kernel<<<dim3(rows / RPB), dim3(TPB), 0, stream>>>(x, imp, out);
}

// Round 10
// 111.418 us; speedup vs baseline: 1.7721x; 1.7721x over previous
//
#include <hip/hip_runtime.h>

#define COLS 2048
#define KSEL 256
#define TPB  256

// LDS word-offsets (one row per block)
#define WOFF  1024      // 4 wave totals
#define BC    1028      // scan broadcast {T, kk, na}
#define BC2   1032      // radix broadcast {T, kk, ne}
#define CNTW  1036      // compact append counter
#define BUF   1040      // compact list, cap 256
#define R2O   1296      // final list, cap 64
#define NWORDS 1360

__device__ __forceinline__ unsigned mbcnt64(unsigned long long m) {
    unsigned c = __builtin_amdgcn_mbcnt_lo((unsigned)m, 0u);
    return __builtin_amdgcn_mbcnt_hi((unsigned)(m >> 32), c);
}

// One block (256 thr) per row; thread t owns cols 8t..8t+7 (thread order =
// column order -> tie-break by lower index works on thread-ordered scans).
// Exact top-K radix select: one 1024-bin pass on score bits[30:21], then
// wave0 ballot-radix on <=64 survivors; exact refine fallbacks for fat bins.
// score = as_uint(x*imp) & 0x7FFFFFFF == bits of |x|*|imp| (monotone in uint).
__global__ __launch_bounds__(TPB)
void CompetitiveSelection_topk_kernel(const float* __restrict__ x,
                                      const float* __restrict__ imp,
                                      float* __restrict__ out)
{
    __shared__ __align__(16) unsigned lds[NWORDS];
    const int tid  = threadIdx.x;
    const int lane = tid & 63;
    const int wid  = tid >> 6;
    const long base = (long)blockIdx.x * COLS + tid * 8;

    // ---- clear hist (1 uint4/thread) + counter ----
    *(uint4*)&lds[4 * tid] = make_uint4(0, 0, 0, 0);
    if (tid == 0) lds[CNTW] = 0;
    __syncthreads();

    // ---- load + score-once + first-pass atomics (bits[30:21], 1024 bins) ----
    float4 xa = *(const float4*)(x + base);
    float4 xb = *(const float4*)(x + base + 4);
    float4 ia = *(const float4*)(imp + tid * 8);
    float4 ib = *(const float4*)(imp + tid * 8 + 4);
    float xs[8] = {xa.x, xa.y, xa.z, xa.w, xb.x, xb.y, xb.z, xb.w};
    float iv[8] = {ia.x, ia.y, ia.z, ia.w, ib.x, ib.y, ib.z, ib.w};
    unsigned sc[8];
#pragma unroll
    for (int j = 0; j < 8; ++j) {
        sc[j] = __float_as_uint(xs[j] * iv[j]) & 0x7FFFFFFFu;
        atomicAdd(&lds[sc[j] >> 21], 1u);
    }
    __syncthreads();

    unsigned T = 0, kk = KSEL, na = 0;
    unsigned hm = 0x80000000u;   // determined bits (bit31 always 0)
    int nb = 31;                 // undetermined low bits

    // block-parallel scanfind over 1024 bins (thread owns bins 4t..4t+3);
    // finds the bin containing rank kk among descending bins, broadcasts.
    auto passScan = [&](int s) {
        uint4 h = *(const uint4*)&lds[4 * tid];
        unsigned cnt[4] = {h.x, h.y, h.z, h.w};
        unsigned tot = cnt[0] + cnt[1] + cnt[2] + cnt[3];
        unsigned S = tot;        // in-wave inclusive suffix over lanes >= lane
#pragma unroll
        for (int off = 1; off < 64; off <<= 1) {
            unsigned u = __shfl_down(S, off);
            if (lane + off < 64) S += u;
        }
        if (lane == 0) lds[WOFF + wid] = S;     // wave total
        __syncthreads();
        unsigned above = S - tot;               // higher bins within my wave
#pragma unroll
        for (int w = 0; w < 4; ++w) above += (w > wid) ? lds[WOFF + w] : 0u;
        int cc = -1; unsigned cab = 0, cnb = 0;
#pragma unroll
        for (int b = 3; b >= 0; --b) {
            if (cc < 0 && above < kk && above + cnt[b] >= kk) {
                cc = 4 * tid + b; cab = above; cnb = cnt[b];
            }
            above += cnt[b];
        }
        if (cc >= 0) {                          // exactly one thread in block
            lds[BC + 0] = T | ((unsigned)cc << s);
            lds[BC + 1] = kk - cab;
            lds[BC + 2] = cnb;
        }
        __syncthreads();
        T = lds[BC + 0]; kk = lds[BC + 1]; na = lds[BC + 2];
        hm |= (0x3FFu << s);
        nb = s;
    };

    passScan(21);

    // ultra-rare: refine from registers while boundary bin > 256
    while (na > 256u && nb > 0) {
        int s = (nb > 10) ? (nb - 10) : 0;
        *(uint4*)&lds[4 * tid] = make_uint4(0, 0, 0, 0);
        __syncthreads();
#pragma unroll
        for (int j = 0; j < 8; ++j)
            if ((sc[j] & hm) == T) atomicAdd(&lds[(sc[j] >> s) & 1023u], 1u);
        __syncthreads();
        passScan(s);
    }

    unsigned ne, nlist = 0;
    if (nb == 0) {
        ne = na;                 // T fully exact, na == #equals
    } else {
        // ---- compact survivors (na <= 256) into BUF ----
        {
            unsigned c = 0;
#pragma unroll
            for (int j = 0; j < 8; ++j) c += ((sc[j] & hm) == T) ? 1u : 0u;
            unsigned S = c;      // in-wave inclusive prefix
#pragma unroll
            for (int off = 1; off < 64; off <<= 1) {
                unsigned u = __shfl_up(S, off);
                if (lane >= off) S += u;
            }
            unsigned rb = 0;
            if (lane == 63) rb = atomicAdd(&lds[CNTW], S);   // wave base
            unsigned p = BUF + __shfl(rb, 63) + S - c;
#pragma unroll
            for (int j = 0; j < 8; ++j)
                if ((sc[j] & hm) == T) lds[p++] = sc[j];
            nlist = na;
        }
        __syncthreads();

        // rare: refine over the compacted list while boundary bin > 64
        while (na > 64u && nb > 0) {
            int s = (nb > 10) ? (nb - 10) : 0;
            *(uint4*)&lds[4 * tid] = make_uint4(0, 0, 0, 0);
            __syncthreads();
            for (int idx = tid; idx < (int)nlist; idx += TPB) {
                unsigned v = lds[BUF + idx];
                if ((v & hm) == T) atomicAdd(&lds[(v >> s) & 1023u], 1u);
            }
            __syncthreads();
            passScan(s);
        }

        if (nb == 0) {
            ne = na;
        } else {
            // ---- wave0: gather <=64 survivors, ballot-radix remaining bits ----
            if (wid == 0) {
                unsigned run2 = 0;
                const unsigned nit = (nlist + 63u) >> 6;
                for (unsigned k = 0; k < nit; ++k) {
                    unsigned idx = (unsigned)lane + 64u * k;
                    bool inb = idx < nlist;
                    unsigned v = inb ? lds[BUF + idx] : 0u;
                    bool act = inb && ((v & hm) == T);
                    unsigned long long m = __ballot(act);
                    if (act) lds[R2O + run2 + mbcnt64(m)] = v;
                    run2 += (unsigned)__popcll(m);
                }
                unsigned v = ((unsigned)lane < na) ? lds[R2O + lane] : 0u;
                unsigned long long M = __ballot((unsigned)lane < na);
                unsigned tl = 0, k2 = kk;
                for (int b = nb - 1; b >= 0; --b) {
                    unsigned long long ones = __ballot((v >> b) & 1u) & M;
                    unsigned c1 = (unsigned)__popcll(ones);
                    if (c1 >= k2) { M = ones; tl |= (1u << b); }
                    else          { M &= ~ones; k2 -= c1; }
                }
                if (lane == 0) {
                    lds[BC2 + 0] = T | tl;
                    lds[BC2 + 1] = k2;                        // rank in equals
                    lds[BC2 + 2] = (unsigned)__popcll(M);     // ne
                }
            }
            __syncthreads();
            T = lds[BC2 + 0]; kk = lds[BC2 + 1]; ne = lds[BC2 + 2];
        }
    }

    // ---- epilogue: T exact; kk = #equals to keep (lowest col first) ----
    float* orow = out + base;
    if (ne == kk) {              // no boundary-tie split (common)
        float4 oa, ob;
        oa.x = (sc[0] >= T) ? xs[0] : 0.0f;
        oa.y = (sc[1] >= T) ? xs[1] : 0.0f;
        oa.z = (sc[2] >= T) ? xs[2] : 0.0f;
        oa.w = (sc[3] >= T) ? xs[3] : 0.0f;
        ob.x = (sc[4] >= T) ? xs[4] : 0.0f;
        ob.y = (sc[5] >= T) ? xs[5] : 0.0f;
        ob.z = (sc[6] >= T) ? xs[6] : 0.0f;
        ob.w = (sc[7] >= T) ? xs[7] : 0.0f;
        *(float4*)(orow)     = oa;
        *(float4*)(orow + 4) = ob;
    } else {
        // tie split: block-ordered exclusive prefix of per-thread equal counts
        unsigned eq = 0;
#pragma unroll
        for (int j = 0; j < 8; ++j) eq += (sc[j] == T) ? 1u : 0u;
        unsigned S = eq;         // in-wave inclusive prefix
#pragma unroll
        for (int off = 1; off < 64; off <<= 1) {
            unsigned u = __shfl_up(S, off);
            if (lane >= off) S += u;
        }
        if (lane == 63) lds[WOFF + wid] = S;   // wave totals (safe post-BC2)
        __syncthreads();
        unsigned add = 0;
#pragma unroll
        for (int w = 0; w < 4; ++w) add += (w < wid) ? lds[WOFF + w] : 0u;
        unsigned ebase = add + S - eq;         // equals in lower columns
        float o[8];
#pragma unroll
        for (int j = 0; j < 8; ++j) {
            bool pick = sc[j] > T;
            if (sc[j] == T) { pick = (ebase < kk); ebase += 1; }
            o[j] = pick ? xs[j] : 0.0f;
        }
        *(float4*)(orow)     = make_float4(o[0], o[1], o[2], o[3]);
        *(float4*)(orow + 4) = make_float4(o[4], o[5], o[6], o[7]);
    }
}

extern "C" void kernel_launch(void* const* d_in, const int* in_sizes, int n_in,
                              void* d_out, int out_size, void* d_ws, size_t ws_size,
                              hipStream_t stream)
{
    const float* x   = (const float*)d_in[0];
    const float* imp = (const float*)d_in[1];
    float* out       = (float*)d_out;

    const int rows = in_sizes[0] / COLS;   // 32768
    CompetitiveSelection_topk_kernel<<<dim3(rows), dim3(TPB), 0, stream>>>(x, imp, out);
}